// Round 3
// baseline (150.292 us; speedup 1.0000x reference)
//
#include <hip/hip_runtime.h>

// Instant-NGP single-level hash grid lookup.
// x: [B,2] f32 in [0,1); table: [524288, 2] f32; out: [B,2] f32.
// idx = (c0 ^ (2654435761*c1)) & (2^19 - 1)  -- exact vs int64 ref since
// TABLE_SIZE is a power of two and corners are nonnegative.
//
// R3: 4 points/thread (16 outstanding gathers/thread for MLP) +
// non-temporal streaming of x/out (native clang vector type — HIP float4
// is a class and rejected by __builtin_nontemporal_*).

#define RESOLUTION 1024.0f
#define TMASK 524287u
#define PI2 2654435761u

typedef float f32x4 __attribute__((ext_vector_type(4)));

struct PointWork {
    unsigned i00, i01, i10, i11;
    float w00, w01, w10, w11;
};

__device__ __forceinline__ PointWork prep(float px, float py) {
    PointWork w;
    float xs0 = px * RESOLUTION;
    float xs1 = py * RESOLUTION;
    float f0 = floorf(xs0);
    float f1 = floorf(xs1);
    unsigned c0 = (unsigned)(int)f0;
    unsigned c1 = (unsigned)(int)f1;
    float d0 = xs0 - f0;
    float d1 = xs1 - f1;
    float e0 = 1.0f - d0;
    float e1 = 1.0f - d1;
    unsigned hb0 = PI2 * c1;
    unsigned hb1 = hb0 + PI2;   // PI2*(c1+1)
    w.i00 = (c0        ^ hb0) & TMASK;
    w.i01 = (c0        ^ hb1) & TMASK;
    w.i10 = ((c0 + 1u) ^ hb0) & TMASK;
    w.i11 = ((c0 + 1u) ^ hb1) & TMASK;
    w.w00 = e0 * e1;
    w.w01 = e0 * d1;
    w.w10 = d0 * e1;
    w.w11 = d0 * d1;
    return w;
}

__global__ __launch_bounds__(256) void ingp_kernel(
    const f32x4* __restrict__ x4,
    const float2* __restrict__ t2,
    f32x4* __restrict__ out4,
    int nthreads)   // nthreads = B/4
{
    int t = blockIdx.x * blockDim.x + threadIdx.x;
    if (t >= nthreads) return;

    // 4 points = 2 float4 loads of x (streaming, keep out of L2)
    f32x4 a = __builtin_nontemporal_load(&x4[2 * t]);
    f32x4 b = __builtin_nontemporal_load(&x4[2 * t + 1]);

    PointWork p0 = prep(a.x, a.y);
    PointWork p1 = prep(a.z, a.w);
    PointWork p2 = prep(b.x, b.y);
    PointWork p3 = prep(b.z, b.w);

    // Issue all 16 gathers before any use (compiler keeps them outstanding)
    float2 t00_0 = t2[p0.i00], t01_0 = t2[p0.i01], t10_0 = t2[p0.i10], t11_0 = t2[p0.i11];
    float2 t00_1 = t2[p1.i00], t01_1 = t2[p1.i01], t10_1 = t2[p1.i10], t11_1 = t2[p1.i11];
    float2 t00_2 = t2[p2.i00], t01_2 = t2[p2.i01], t10_2 = t2[p2.i10], t11_2 = t2[p2.i11];
    float2 t00_3 = t2[p3.i00], t01_3 = t2[p3.i01], t10_3 = t2[p3.i10], t11_3 = t2[p3.i11];

    f32x4 o01, o23;
    o01.x = t00_0.x * p0.w00 + t01_0.x * p0.w01 + t10_0.x * p0.w10 + t11_0.x * p0.w11;
    o01.y = t00_0.y * p0.w00 + t01_0.y * p0.w01 + t10_0.y * p0.w10 + t11_0.y * p0.w11;
    o01.z = t00_1.x * p1.w00 + t01_1.x * p1.w01 + t10_1.x * p1.w10 + t11_1.x * p1.w11;
    o01.w = t00_1.y * p1.w00 + t01_1.y * p1.w01 + t10_1.y * p1.w10 + t11_1.y * p1.w11;
    o23.x = t00_2.x * p2.w00 + t01_2.x * p2.w01 + t10_2.x * p2.w10 + t11_2.x * p2.w11;
    o23.y = t00_2.y * p2.w00 + t01_2.y * p2.w01 + t10_2.y * p2.w10 + t11_2.y * p2.w11;
    o23.z = t00_3.x * p3.w00 + t01_3.x * p3.w01 + t10_3.x * p3.w10 + t11_3.x * p3.w11;
    o23.w = t00_3.y * p3.w00 + t01_3.y * p3.w01 + t10_3.y * p3.w10 + t11_3.y * p3.w11;

    __builtin_nontemporal_store(o01, &out4[2 * t]);
    __builtin_nontemporal_store(o23, &out4[2 * t + 1]);
}

extern "C" void kernel_launch(void* const* d_in, const int* in_sizes, int n_in,
                              void* d_out, int out_size, void* d_ws, size_t ws_size,
                              hipStream_t stream) {
    const float* x     = (const float*)d_in[0];
    const float* table = (const float*)d_in[1];
    float* out         = (float*)d_out;
    const int batch = in_sizes[0] / 2;       // 4194304
    const int nthreads = batch / 4;          // 4 points per thread (batch % 4 == 0)

    const int block = 256;
    const int grid = (nthreads + block - 1) / block;
    ingp_kernel<<<grid, block, 0, stream>>>(
        (const f32x4*)x, (const float2*)table, (f32x4*)out, nthreads);
}

// Round 4
// 129.314 us; speedup vs baseline: 1.1622x; 1.1622x over previous
//
#include <hip/hip_runtime.h>

// Instant-NGP single-level hash grid lookup.
// x: [B,2] f32 in [0,1); table: [524288, 2] f32; out: [B,2] f32.
// idx = (c0 ^ (2654435761*c1)) & (2^19 - 1)  -- exact vs int64 ref since
// TABLE_SIZE is a power of two and corners are nonnegative.
//
// R4: revert ALL nontemporal hints (R3 regression suspect). 2 points/thread:
// x loaded as one float4, out stored as one float4 (half the streaming
// instructions of R1), 8 gathers issued before any use (2x MLP of R1).
// Gather order i00,i10,i01,i11: for even c0 the pairs share a 128B line,
// so the second access of each pair hits L1.

#define RESOLUTION 1024.0f
#define TMASK 524287u
#define PI2 2654435761u

typedef float f32x4 __attribute__((ext_vector_type(4)));

struct PointWork {
    unsigned i00, i01, i10, i11;
    float w00, w01, w10, w11;
};

__device__ __forceinline__ PointWork prep(float px, float py) {
    PointWork w;
    float xs0 = px * RESOLUTION;
    float xs1 = py * RESOLUTION;
    float f0 = floorf(xs0);
    float f1 = floorf(xs1);
    unsigned c0 = (unsigned)(int)f0;
    unsigned c1 = (unsigned)(int)f1;
    float d0 = xs0 - f0;
    float d1 = xs1 - f1;
    float e0 = 1.0f - d0;
    float e1 = 1.0f - d1;
    unsigned hb0 = PI2 * c1;
    unsigned hb1 = hb0 + PI2;   // PI2*(c1+1)
    w.i00 = (c0        ^ hb0) & TMASK;
    w.i01 = (c0        ^ hb1) & TMASK;
    w.i10 = ((c0 + 1u) ^ hb0) & TMASK;
    w.i11 = ((c0 + 1u) ^ hb1) & TMASK;
    w.w00 = e0 * e1;
    w.w01 = e0 * d1;
    w.w10 = d0 * e1;
    w.w11 = d0 * d1;
    return w;
}

__global__ __launch_bounds__(256) void ingp_kernel(
    const f32x4* __restrict__ x4,
    const float2* __restrict__ t2,
    f32x4* __restrict__ out4,
    int nthreads)   // nthreads = B/2
{
    int t = blockIdx.x * blockDim.x + threadIdx.x;
    if (t >= nthreads) return;

    // 2 points = 1 float4 load of x (coalesced, 16B/lane)
    f32x4 a = x4[t];

    PointWork p0 = prep(a.x, a.y);
    PointWork p1 = prep(a.z, a.w);

    // Issue all 8 gathers before any use; pair order exploits even-c0
    // same-line adjacency via L1.
    float2 t00_0 = t2[p0.i00], t10_0 = t2[p0.i10], t01_0 = t2[p0.i01], t11_0 = t2[p0.i11];
    float2 t00_1 = t2[p1.i00], t10_1 = t2[p1.i10], t01_1 = t2[p1.i01], t11_1 = t2[p1.i11];

    f32x4 o;
    o.x = t00_0.x * p0.w00 + t01_0.x * p0.w01 + t10_0.x * p0.w10 + t11_0.x * p0.w11;
    o.y = t00_0.y * p0.w00 + t01_0.y * p0.w01 + t10_0.y * p0.w10 + t11_0.y * p0.w11;
    o.z = t00_1.x * p1.w00 + t01_1.x * p1.w01 + t10_1.x * p1.w10 + t11_1.x * p1.w11;
    o.w = t00_1.y * p1.w00 + t01_1.y * p1.w01 + t10_1.y * p1.w10 + t11_1.y * p1.w11;

    out4[t] = o;
}

extern "C" void kernel_launch(void* const* d_in, const int* in_sizes, int n_in,
                              void* d_out, int out_size, void* d_ws, size_t ws_size,
                              hipStream_t stream) {
    const float* x     = (const float*)d_in[0];
    const float* table = (const float*)d_in[1];
    float* out         = (float*)d_out;
    const int batch = in_sizes[0] / 2;       // 4194304
    const int nthreads = batch / 2;          // 2 points per thread

    const int block = 256;
    const int grid = (nthreads + block - 1) / block;
    ingp_kernel<<<grid, block, 0, stream>>>(
        (const f32x4*)x, (const float2*)table, (f32x4*)out, nthreads);
}

// Round 5
// 128.318 us; speedup vs baseline: 1.1712x; 1.0078x over previous
//
#include <hip/hip_runtime.h>

// Instant-NGP single-level hash grid lookup.
// x: [B,2] f32 in [0,1); table: [524288, 2] f32; out: [B,2] f32.
// idx = (c0 ^ (2654435761*c1)) & (2^19 - 1)  -- exact vs int64 ref since
// TABLE_SIZE is a power of two and corners are nonnegative.
//
// R5: paired float4 gathers. For even c0, i10 = i00^1 and i11 = i01^1 are
// the other half of the same aligned 16B entry-pair, so one float4 load
// covers both corners. Always load the two float4 pairs; only odd-c0 lanes
// (exec-masked, ~half) issue the 2 extra float2 gathers.
// Avg probes/point: 4 -> 3; L2 line traffic unchanged (~3 lines/point).

#define RESOLUTION 1024.0f
#define TMASK 524287u
#define PI2 2654435761u

typedef float f32x4 __attribute__((ext_vector_type(4)));

__device__ __forceinline__ float2 ingp_point(const float2* __restrict__ t2,
                                             const f32x4* __restrict__ t4,
                                             float px, float py) {
    float xs0 = px * RESOLUTION;
    float xs1 = py * RESOLUTION;
    float f0 = floorf(xs0);
    float f1 = floorf(xs1);
    unsigned c0 = (unsigned)(int)f0;
    unsigned c1 = (unsigned)(int)f1;
    float d0 = xs0 - f0;
    float d1 = xs1 - f1;
    float e0 = 1.0f - d0;
    float e1 = 1.0f - d1;

    unsigned hb0 = PI2 * c1;
    unsigned hb1 = hb0 + PI2;              // PI2*(c1+1)
    unsigned i00 = (c0 ^ hb0) & TMASK;
    unsigned i01 = (c0 ^ hb1) & TMASK;

    // Aligned-pair loads: entry pair {i&~1, i|1} in one float4.
    f32x4 A = t4[i00 >> 1];
    f32x4 B = t4[i01 >> 1];
    unsigned a_hi = i00 & 1u;
    unsigned b_hi = i01 & 1u;

    float2 f00 = a_hi ? make_float2(A.z, A.w) : make_float2(A.x, A.y);
    float2 f01 = b_hi ? make_float2(B.z, B.w) : make_float2(B.x, B.y);

    float2 f10, f11;
    if (c0 & 1u) {
        // odd c0: corner c0+1 hashes to an unrelated entry -> 2 extra gathers
        unsigned i10 = ((c0 + 1u) ^ hb0) & TMASK;
        unsigned i11 = ((c0 + 1u) ^ hb1) & TMASK;
        f10 = t2[i10];
        f11 = t2[i11];
    } else {
        // even c0: i10 = i00^1, i11 = i01^1 -> other half of A/B
        f10 = a_hi ? make_float2(A.x, A.y) : make_float2(A.z, A.w);
        f11 = b_hi ? make_float2(B.x, B.y) : make_float2(B.z, B.w);
    }

    float w00 = e0 * e1;
    float w01 = e0 * d1;
    float w10 = d0 * e1;
    float w11 = d0 * d1;

    float ox = f00.x * w00 + f01.x * w01 + f10.x * w10 + f11.x * w11;
    float oy = f00.y * w00 + f01.y * w01 + f10.y * w10 + f11.y * w11;
    return make_float2(ox, oy);
}

__global__ __launch_bounds__(256) void ingp_kernel(
    const f32x4* __restrict__ x4,
    const float2* __restrict__ t2,
    const f32x4* __restrict__ t4,
    f32x4* __restrict__ out4,
    int nthreads)   // nthreads = B/2
{
    int t = blockIdx.x * blockDim.x + threadIdx.x;
    if (t >= nthreads) return;

    f32x4 a = x4[t];   // 2 points, coalesced 16B/lane

    float2 o0 = ingp_point(t2, t4, a.x, a.y);
    float2 o1 = ingp_point(t2, t4, a.z, a.w);

    f32x4 o;
    o.x = o0.x; o.y = o0.y; o.z = o1.x; o.w = o1.y;
    out4[t] = o;
}

extern "C" void kernel_launch(void* const* d_in, const int* in_sizes, int n_in,
                              void* d_out, int out_size, void* d_ws, size_t ws_size,
                              hipStream_t stream) {
    const float* x     = (const float*)d_in[0];
    const float* table = (const float*)d_in[1];
    float* out         = (float*)d_out;
    const int batch = in_sizes[0] / 2;       // 4194304
    const int nthreads = batch / 2;          // 2 points per thread

    const int block = 256;
    const int grid = (nthreads + block - 1) / block;
    ingp_kernel<<<grid, block, 0, stream>>>(
        (const f32x4*)x, (const float2*)table, (const f32x4*)table,
        (f32x4*)out, nthreads);
}